// Round 15
// baseline (67.961 us; speedup 1.0000x reference)
//
#include <hip/hip_runtime.h>
#include <stdint.h>

#define WIN 8
#define DEG 16
#define ORDER 500
#define STEPS_C 50
#define T1 51          // STEPS+1
#define FRD 15         // feature rows = 2*WIN-1
#define NI 8           // adj_bits words per node
#define WPB 100        // walkers per block (5*100 = 500 exactly)
#define BPG 5          // blocks per graph
#define BLOCK 512
#define MSTR 17        // mask row stride in u64 (odd -> conflict-free)
#define NSTR 52        // nodes/eidx row stride (elements)

typedef float vfloat4 __attribute__((ext_vector_type(4)));  // native vec for nt-store

// r15 = r14 with the nontemporal builtin applied to a clang native float4
// (HIP_vector_type is not accepted by __builtin_nontemporal_store).
//  - dedicated mask region (61.2 KB static LDS < 64 KB): no overlay, one barrier
//  - steady-state walk split: t>=7 has all window slots valid -> vk chains
//    vanish for 43 of 50 steps
//  - nontemporal (evict-first) output stores: streaming writes don't evict
//    the graph tables re-read by same-XCD sibling blocks
//
// LDS layout (61200 B, 2 blocks/CU; grid 500 -> one resident generation):
//   [0,16000)     g_adj   u16[500][16] (local ids)
//   [16000,32000) g_bits  int[500][8]
//   [32000,45600) mask_l  u64[100][17]
//   [45600,56000) nodes_l u16[100][52]
//   [56000,61200) eidx_l  u8[100][52]
__global__ __launch_bounds__(512)
void fused_kernel(const int* __restrict__ adj_nodes,
                  const int* __restrict__ adj_bits,
                  const int* __restrict__ choices,
                  float* __restrict__ out, int N)
{
    __shared__ unsigned long long smem[7650];   // 61200 B
    unsigned short* g_adj   = (unsigned short*)smem;
    int*            g_bits  = (int*)((char*)smem + 16000);
    unsigned long long* mask_l = (unsigned long long*)((char*)smem + 32000);
    unsigned short* nodes_l = (unsigned short*)((char*)smem + 45600);
    unsigned char*  eidx_l  = (unsigned char*)((char*)smem + 56000);

    const int tid = threadIdx.x;

    // bijective XCD-aware swizzle (m204): nwg=500 -> q=62, r=4
    const int nwg = gridDim.x;
    const int q8  = nwg >> 3, r8 = nwg & 7;
    const int xcd = blockIdx.x & 7, ord = blockIdx.x >> 3;
    const int vb  = (xcd < r8 ? xcd * (q8 + 1) : r8 * (q8 + 1) + (xcd - r8) * q8) + ord;

    const int graph  = vb / BPG;
    const int lb     = vb - graph * BPG;
    const int gbase  = graph * ORDER;
    const int lstart = lb * WPB + tid;       // local walker id in graph
    const bool act   = (tid < WPB);
    const int wi     = gbase + lstart;
    const int wild   = act ? wi : gbase;     // safe load index
    const int wbase  = gbase + lb * WPB;     // first global walker of block

    // ---- stage graph tables into LDS (coalesced) ----
    {
        const int4* src = (const int4*)(adj_nodes + (size_t)gbase * DEG);
        unsigned* dst = (unsigned*)g_adj;
        for (int c = tid; c < ORDER * DEG / 4; c += BLOCK) {
            const int4 v = src[c];
            dst[2 * c + 0] = (unsigned)(v.x - gbase) | ((unsigned)(v.y - gbase) << 16);
            dst[2 * c + 1] = (unsigned)(v.z - gbase) | ((unsigned)(v.w - gbase) << 16);
        }
        int4* db = (int4*)g_bits;
        const int4* sb = (const int4*)(adj_bits + (size_t)gbase * NI);
        for (int c = tid; c < ORDER * NI / 4; c += BLOCK) db[c] = sb[c];
    }
    __syncthreads();

    // ---- walk phase (walker-per-thread; masks in registers) ----
    unsigned long long idm[WIN];
    unsigned long long adm[WIN - 1];
#pragma unroll
    for (int k = 0; k < WIN; k++) idm[k] = 0ull;
#pragma unroll
    for (int k = 0; k < WIN - 1; k++) adm[k] = 0ull;

    if (act) {
        int w[WIN];
#pragma unroll
        for (int k = 0; k < WIN; k++) w[k] = 0;
        w[7] = lstart;

        nodes_l[tid * NSTR] = (unsigned short)lstart;   // row t=0 (local id)

        // depth-8 rolling register prefetch of choices (coalesced, named regs)
        int c0 = choices[wild];
        int c1 = choices[(size_t)1 * N + wild];
        int c2 = choices[(size_t)2 * N + wild];
        int c3 = choices[(size_t)3 * N + wild];
        int c4 = choices[(size_t)4 * N + wild];
        int c5 = choices[(size_t)5 * N + wild];
        int c6 = choices[(size_t)6 * N + wild];
        int c7 = choices[(size_t)7 * N + wild];

        // body; `steady` is a literal at each call site -> const-folded
        auto step = [&](const int t, const bool steady) {
            const int ch = c0;
            c0 = c1; c1 = c2; c2 = c3; c3 = c4; c4 = c5; c5 = c6; c6 = c7;
            c7 = (t + 8 < STEPS_C) ? choices[(size_t)(t + 8) * N + wild] : 0;

            // deg==16 pow2: floored mod == AND (valid for negatives)
            const int e = ch & (DEG - 1);
            int r15 = ch % (DEG - 1); if (r15 < 0) r15 += (DEG - 1);
            const int e2 = (e + 1 + r15) & (DEG - 1);

            const int cur = w[7];
            const int n1 = g_adj[cur * DEG + e];
            const int n2 = g_adj[cur * DEG + e2];

            const bool bt = (steady || t >= 1) && (n1 == w[6]);
            const int nn = bt ? n2 : n1;        // local id
            const int ee = bt ? e2 : e;         // edge index [0,16)

            // cid == local id directly (node_id closed form)
            const unsigned q  = (unsigned)nn / 63u;
            const unsigned rr = (unsigned)nn - q * 63u;
            const unsigned s  = rr > 31u ? 31u : rr;    // int32 saturating shift
            const unsigned long long bitpos = 1ull << (t + 1);

#pragma unroll
            for (int k = 0; k < WIN; k++) {
                const bool vk = steady || ((k + t) >= (WIN - 1));
                if (vk && (w[k] == nn)) idm[k] |= bitpos;
            }
#pragma unroll
            for (int k = 0; k < WIN - 1; k++) {
                const bool vk = steady || ((k + t) >= (WIN - 1));
                const int word = g_bits[w[k] * NI + q];
                if (vk && ((word >> s) & 1)) adm[k] |= bitpos;
            }

#pragma unroll
            for (int k = 0; k < WIN - 1; k++) w[k] = w[k + 1];
            w[7] = nn;

            nodes_l[tid * NSTR + t + 1] = (unsigned short)nn;
            eidx_l[tid * NSTR + t]      = (unsigned char)ee;
        };

        for (int t = 0; t < WIN - 1; t++)       step(t, false);
        for (int t = WIN - 1; t < STEPS_C; t++) step(t, true);

        // masks to their dedicated region (no overlay, no extra barrier)
#pragma unroll
        for (int k = 0; k < WIN; k++)      mask_l[tid * MSTR + k]     = idm[k];
#pragma unroll
        for (int k = 0; k < WIN - 1; k++)  mask_l[tid * MSTR + 8 + k] = adm[k];
    }
    __syncthreads();

    // ---- expand phase: all 512 threads, pure float4 nt streams (aligned) ----

    // out0: walk_nodes [wl][51] = gbase + nodes_l[wl][t]   (5100 floats)
    {
        float* dst = out + (size_t)wbase * T1;
        const int n4 = (WPB * T1) >> 2;          // 1275
        for (int c = tid; c < n4; c += BLOCK) {
            const int f0 = c << 2;
            int wl = f0 / T1, t = f0 - wl * T1;
            vfloat4 v;
#pragma unroll
            for (int u = 0; u < 4; u++) {
                v[u] = (float)(gbase + (int)nodes_l[wl * NSTR + t]);
                t++; if (t == T1) { t = 0; wl++; }
            }
            __builtin_nontemporal_store(v, reinterpret_cast<vfloat4*>(dst + f0));
        }
    }

    // out1: walk_edges [wl][50] = ((gbase+cur)<<4)+eidx   (5000 floats, <2^24 exact)
    {
        float* dst = out + (size_t)N * T1 + (size_t)wbase * STEPS_C;
        const int n4 = (WPB * STEPS_C) >> 2;     // 1250
        for (int c = tid; c < n4; c += BLOCK) {
            const int f0 = c << 2;
            int wl = f0 / STEPS_C, t = f0 - wl * STEPS_C;
            vfloat4 v;
#pragma unroll
            for (int u = 0; u < 4; u++) {
                v[u] = (float)((((gbase + (int)nodes_l[wl * NSTR + t])) << 4)
                               + (int)eidx_l[wl * NSTR + t]);
                t++; if (t == STEPS_C) { t = 0; wl++; }
            }
            __builtin_nontemporal_store(v, reinterpret_cast<vfloat4*>(dst + f0));
        }
    }

    // out2: walk_x [wl][j<15][t<51] = bit t of mask_l[wl][j]   (76500 floats)
    {
        float* dst = out + (size_t)N * (T1 + STEPS_C) + (size_t)wbase * (FRD * T1);
        const int n4 = (WPB * FRD * T1) >> 2;    // 19125
        for (int c = tid; c < n4; c += BLOCK) {
            const int f0 = c << 2;
            int wl = f0 / (FRD * T1), rem = f0 - wl * (FRD * T1);
            int j = rem / T1, t = rem - j * T1;
            vfloat4 v;
#pragma unroll
            for (int u = 0; u < 4; u++) {
                v[u] = ((mask_l[wl * MSTR + j] >> t) & 1ull) ? 1.0f : 0.0f;
                t++;
                if (t == T1) { t = 0; j++; if (j == FRD) { j = 0; wl++; } }
            }
            __builtin_nontemporal_store(v, reinterpret_cast<vfloat4*>(dst + f0));
        }
    }
}

extern "C" void kernel_launch(void* const* d_in, const int* in_sizes, int n_in,
                              void* d_out, int out_size, void* d_ws, size_t ws_size,
                              hipStream_t stream) {
    const int N = in_sizes[3];               // 50000
    const int num_graphs = N / ORDER;        // 100
    const int grid = num_graphs * BPG;       // 500 blocks, 100 walkers each

    fused_kernel<<<grid, BLOCK, 0, stream>>>(
        (const int*)d_in[0], (const int*)d_in[4], (const int*)d_in[5],
        (float*)d_out, N);
}

// Round 16
// 49.197 us; speedup vs baseline: 1.3814x; 1.3814x over previous
//
#include <hip/hip_runtime.h>
#include <stdint.h>

#define WIN 8
#define DEG 16
#define ORDER 500
#define STEPS_C 50
#define T1 51          // STEPS+1
#define FRD 15         // feature rows = 2*WIN-1
#define NI 8           // adj_bits words per node
#define WPB 100        // walkers per block (5*100 = 500 exactly)
#define BPG 5          // blocks per graph
#define BLOCK 512
#define MSTR 17        // mask row stride in u64 (odd -> conflict-free)
#define NSTR 52        // nodes/eidx row stride (elements)

// r16 = r13 verbatim (49.7 us verified: 47.6 KB LDS -> 3 blocks/CU cap, one
// resident generation, plain float4 stores, mask overlay + two barriers)
// + ONE change: steady-state walk split — for t >= 7 all window slots are
// valid, so the vk compare/select chains vanish for 43 of 50 steps.
//
// LDS time-union (47600 B):
//   walk phase:   [0,16000) g_adj u16 | [16000,32000) g_bits int
//   expand phase: [0,13600) mask_l u64[100][17]  (tables dead by then)
//   both:         [32000,42400) nodes_l u16[100][52]
//                 [42400,47600) eidx_l  u8[100][52]
__global__ __launch_bounds__(512)
void fused_kernel(const int* __restrict__ adj_nodes,
                  const int* __restrict__ adj_bits,
                  const int* __restrict__ choices,
                  float* __restrict__ out, int N)
{
    __shared__ unsigned long long smem[5950];   // 47600 B
    unsigned short* g_adj   = (unsigned short*)smem;
    int*            g_bits  = (int*)((char*)smem + 16000);
    unsigned long long* mask_l = smem;          // overlays tables after walk
    unsigned short* nodes_l = (unsigned short*)((char*)smem + 32000);
    unsigned char*  eidx_l  = (unsigned char*)((char*)smem + 42400);

    const int tid = threadIdx.x;

    // bijective XCD-aware swizzle (m204): nwg=500 -> q=62, r=4
    const int nwg = gridDim.x;
    const int q8  = nwg >> 3, r8 = nwg & 7;
    const int xcd = blockIdx.x & 7, ord = blockIdx.x >> 3;
    const int vb  = (xcd < r8 ? xcd * (q8 + 1) : r8 * (q8 + 1) + (xcd - r8) * q8) + ord;

    const int graph  = vb / BPG;
    const int lb     = vb - graph * BPG;
    const int gbase  = graph * ORDER;
    const int lstart = lb * WPB + tid;       // local walker id in graph
    const bool act   = (tid < WPB);
    const int wi     = gbase + lstart;
    const int wild   = act ? wi : gbase;     // safe load index
    const int wbase  = gbase + lb * WPB;     // first global walker of block

    // ---- stage graph tables into LDS (coalesced) ----
    {
        const int4* src = (const int4*)(adj_nodes + (size_t)gbase * DEG);
        unsigned* dst = (unsigned*)g_adj;
        for (int c = tid; c < ORDER * DEG / 4; c += BLOCK) {
            const int4 v = src[c];
            dst[2 * c + 0] = (unsigned)(v.x - gbase) | ((unsigned)(v.y - gbase) << 16);
            dst[2 * c + 1] = (unsigned)(v.z - gbase) | ((unsigned)(v.w - gbase) << 16);
        }
        int4* db = (int4*)g_bits;
        const int4* sb = (const int4*)(adj_bits + (size_t)gbase * NI);
        for (int c = tid; c < ORDER * NI / 4; c += BLOCK) db[c] = sb[c];
    }
    __syncthreads();

    // ---- walk phase (walker-per-thread; masks in registers) ----
    unsigned long long idm[WIN];
    unsigned long long adm[WIN - 1];
#pragma unroll
    for (int k = 0; k < WIN; k++) idm[k] = 0ull;
#pragma unroll
    for (int k = 0; k < WIN - 1; k++) adm[k] = 0ull;

    if (act) {
        int w[WIN];
#pragma unroll
        for (int k = 0; k < WIN; k++) w[k] = 0;
        w[7] = lstart;

        nodes_l[tid * NSTR] = (unsigned short)lstart;   // row t=0 (local id)

        // depth-8 rolling register prefetch of choices (coalesced, named regs)
        int c0 = choices[wild];
        int c1 = choices[(size_t)1 * N + wild];
        int c2 = choices[(size_t)2 * N + wild];
        int c3 = choices[(size_t)3 * N + wild];
        int c4 = choices[(size_t)4 * N + wild];
        int c5 = choices[(size_t)5 * N + wild];
        int c6 = choices[(size_t)6 * N + wild];
        int c7 = choices[(size_t)7 * N + wild];

        // body; `steady` is a literal at each call site -> const-folded
        auto step = [&](const int t, const bool steady) {
            const int ch = c0;
            c0 = c1; c1 = c2; c2 = c3; c3 = c4; c4 = c5; c5 = c6; c6 = c7;
            c7 = (t + 8 < STEPS_C) ? choices[(size_t)(t + 8) * N + wild] : 0;

            // deg==16 pow2: floored mod == AND (valid for negatives)
            const int e = ch & (DEG - 1);
            int r15 = ch % (DEG - 1); if (r15 < 0) r15 += (DEG - 1);
            const int e2 = (e + 1 + r15) & (DEG - 1);

            const int cur = w[7];
            const int n1 = g_adj[cur * DEG + e];
            const int n2 = g_adj[cur * DEG + e2];

            const bool bt = (steady || t >= 1) && (n1 == w[6]);
            const int nn = bt ? n2 : n1;        // local id
            const int ee = bt ? e2 : e;         // edge index [0,16)

            // cid == local id directly (node_id closed form)
            const unsigned q  = (unsigned)nn / 63u;
            const unsigned rr = (unsigned)nn - q * 63u;
            const unsigned s  = rr > 31u ? 31u : rr;    // int32 saturating shift
            const unsigned long long bitpos = 1ull << (t + 1);

#pragma unroll
            for (int k = 0; k < WIN; k++) {
                const bool vk = steady || ((k + t) >= (WIN - 1));
                if (vk && (w[k] == nn)) idm[k] |= bitpos;
            }
#pragma unroll
            for (int k = 0; k < WIN - 1; k++) {
                const bool vk = steady || ((k + t) >= (WIN - 1));
                const int word = g_bits[w[k] * NI + q];
                if (vk && ((word >> s) & 1)) adm[k] |= bitpos;
            }

#pragma unroll
            for (int k = 0; k < WIN - 1; k++) w[k] = w[k + 1];
            w[7] = nn;

            nodes_l[tid * NSTR + t + 1] = (unsigned short)nn;
            eidx_l[tid * NSTR + t]      = (unsigned char)ee;
        };

        for (int t = 0; t < WIN - 1; t++)       step(t, false);
        for (int t = WIN - 1; t < STEPS_C; t++) step(t, true);
    }

    // tables are dead from here; barrier, then overlay masks into region A
    __syncthreads();
    if (act) {
#pragma unroll
        for (int k = 0; k < WIN; k++)      mask_l[tid * MSTR + k]     = idm[k];
#pragma unroll
        for (int k = 0; k < WIN - 1; k++)  mask_l[tid * MSTR + 8 + k] = adm[k];
    }
    __syncthreads();

    // ---- expand phase: all 512 threads, pure float4 streams (aligned) ----

    // out0: walk_nodes [wl][51] = gbase + nodes_l[wl][t]   (5100 floats)
    {
        float* dst = out + (size_t)wbase * T1;
        const int n4 = (WPB * T1) >> 2;          // 1275
        for (int c = tid; c < n4; c += BLOCK) {
            const int f0 = c << 2;
            int wl = f0 / T1, t = f0 - wl * T1;
            float vv[4];
#pragma unroll
            for (int u = 0; u < 4; u++) {
                vv[u] = (float)(gbase + (int)nodes_l[wl * NSTR + t]);
                t++; if (t == T1) { t = 0; wl++; }
            }
            float4 v; v.x = vv[0]; v.y = vv[1]; v.z = vv[2]; v.w = vv[3];
            *reinterpret_cast<float4*>(dst + f0) = v;
        }
    }

    // out1: walk_edges [wl][50] = ((gbase+cur)<<4)+eidx   (5000 floats, <2^24 exact)
    {
        float* dst = out + (size_t)N * T1 + (size_t)wbase * STEPS_C;
        const int n4 = (WPB * STEPS_C) >> 2;     // 1250
        for (int c = tid; c < n4; c += BLOCK) {
            const int f0 = c << 2;
            int wl = f0 / STEPS_C, t = f0 - wl * STEPS_C;
            float vv[4];
#pragma unroll
            for (int u = 0; u < 4; u++) {
                vv[u] = (float)((((gbase + (int)nodes_l[wl * NSTR + t])) << 4)
                                + (int)eidx_l[wl * NSTR + t]);
                t++; if (t == STEPS_C) { t = 0; wl++; }
            }
            float4 v; v.x = vv[0]; v.y = vv[1]; v.z = vv[2]; v.w = vv[3];
            *reinterpret_cast<float4*>(dst + f0) = v;
        }
    }

    // out2: walk_x [wl][j<15][t<51] = bit t of mask_l[wl][j]   (76500 floats)
    {
        float* dst = out + (size_t)N * (T1 + STEPS_C) + (size_t)wbase * (FRD * T1);
        const int n4 = (WPB * FRD * T1) >> 2;    // 19125
        for (int c = tid; c < n4; c += BLOCK) {
            const int f0 = c << 2;
            int wl = f0 / (FRD * T1), rem = f0 - wl * (FRD * T1);
            int j = rem / T1, t = rem - j * T1;
            float vv[4];
#pragma unroll
            for (int u = 0; u < 4; u++) {
                vv[u] = ((mask_l[wl * MSTR + j] >> t) & 1ull) ? 1.0f : 0.0f;
                t++;
                if (t == T1) { t = 0; j++; if (j == FRD) { j = 0; wl++; } }
            }
            float4 v; v.x = vv[0]; v.y = vv[1]; v.z = vv[2]; v.w = vv[3];
            *reinterpret_cast<float4*>(dst + f0) = v;
        }
    }
}

extern "C" void kernel_launch(void* const* d_in, const int* in_sizes, int n_in,
                              void* d_out, int out_size, void* d_ws, size_t ws_size,
                              hipStream_t stream) {
    const int N = in_sizes[3];               // 50000
    const int num_graphs = N / ORDER;        // 100
    const int grid = num_graphs * BPG;       // 500 blocks, 100 walkers each

    fused_kernel<<<grid, BLOCK, 0, stream>>>(
        (const int*)d_in[0], (const int*)d_in[4], (const int*)d_in[5],
        (float*)d_out, N);
}